// Round 18
// baseline (88.701 us; speedup 1.0000x reference)
//
#include <hip/hip_runtime.h>
#include <hip/hip_bf16.h>

// ---- problem constants ----
#define D_    1024
#define H_    8
#define N_    16
#define B_    4
#define S_    1024
#define TOK   (B_*S_)       // 4096 tokens
#define NPROJ 2304          // 2048 (perm) + 128 (gate) + 128 (input)
#define CHUNK 32
#define NCHUNK (S_/CHUNK)   // 32
#define NCHAIN (B_*H_)      // 32

typedef __attribute__((ext_vector_type(8))) short bf16x8;
typedef __attribute__((ext_vector_type(4))) float f32x4;

typedef __attribute__((address_space(3))) void       as3_void;
typedef const __attribute__((address_space(1))) void as1_void;

__device__ __forceinline__ void gload_lds16(const void* g, void* l) {
    __builtin_amdgcn_global_load_lds((as1_void*)g, (as3_void*)l, 16, 0, 0);
}

__device__ __forceinline__ short f2bf(float f) {
    unsigned u = __builtin_bit_cast(unsigned, f);
    unsigned r = 0x7FFFu + ((u >> 16) & 1u);
    return (short)((u + r) >> 16);
}
__device__ __forceinline__ float bf2f(short s) {
    unsigned u = ((unsigned)(unsigned short)s) << 16;
    return __builtin_bit_cast(float, u);
}

// single-instruction lane swizzle (xor patterns within 32-lane halves)
template <int IMM>
__device__ __forceinline__ float swzf(float x) {
    return __builtin_bit_cast(float,
        __builtin_amdgcn_ds_swizzle(__builtin_bit_cast(int, x), IMM));
}
// cross-32-lane pull with precomputed byte address
__device__ __forceinline__ float bpermf(int addr, float x) {
    return __builtin_bit_cast(float,
        __builtin_amdgcn_ds_bpermute(addr, __builtin_bit_cast(int, x)));
}
// DPP lane move (VALU pipe, no LDS): CTRL = quad_perm/row op encoding
template <int CTRL>
__device__ __forceinline__ float dppmov(float x) {
    return __builtin_bit_cast(float,
        __builtin_amdgcn_update_dpp(0, __builtin_bit_cast(int, x),
                                    CTRL, 0xF, 0xF, true));
}
#define DPP_QX1  0xB1   // quad_perm [1,0,3,2]  : xor 1
#define DPP_QX2  0x4E   // quad_perm [2,3,0,1]  : xor 2
#define DPP_HMIR 0x141  // row_half_mirror      : completes 8-lane reduce
#define DPP_ROR8 0x128  // row_ror:8            : xor 8 within 16-lane row

// ---------------------------------------------------------------------------
// K1: merged {weight transpose-casts + LayerNorm}, range-decoded 1D grid:
//   [0,2048) Wp | [2048,2176) Wg | [2176,2304) Wi | [2304,2432) Wo
//   [2432,6528) LayerNorm row (id-2432) -> xn
// ---------------------------------------------------------------------------
__global__ __launch_bounds__(256) void prep_kernel(const float* __restrict__ Wp,
                                                   const float* __restrict__ Wg,
                                                   const float* __restrict__ Wi,
                                                   const float* __restrict__ Wo,
                                                   short* __restrict__ WcatT,
                                                   short* __restrict__ WoT,
                                                   const float* __restrict__ x,
                                                   const float* __restrict__ lnw,
                                                   const float* __restrict__ lnb,
                                                   short* __restrict__ xn) {
    int id = blockIdx.x;
    if (id < 2432) {
        const float* src; short* dst; int srcW, Ksz, n_off, bx, by;
        if (id < 2048)      { src = Wp; dst = WcatT; srcW = 2048; Ksz = 1024; n_off = 0;
                              bx = id & 63;  by = id >> 6; }
        else if (id < 2176) { int q = id - 2048; src = Wg; dst = WcatT; srcW = 128; Ksz = 1024;
                              n_off = 2048; bx = q & 3; by = q >> 2; }
        else if (id < 2304) { int q = id - 2176; src = Wi; dst = WcatT; srcW = 128; Ksz = 1024;
                              n_off = 2176; bx = q & 3; by = q >> 2; }
        else                { int q = id - 2304; src = Wo; dst = WoT; srcW = 1024; Ksz = 128;
                              n_off = 0; bx = q & 31; by = q >> 5; }
        __shared__ float tile[32][33];
        int n0 = bx * 32, k0 = by * 32;
        int r  = threadIdx.x >> 3;
        int c4 = (threadIdx.x & 7) * 4;
        float4 v = *(const float4*)(src + (size_t)(k0 + r) * srcW + n0 + c4);
        tile[r][c4+0] = v.x; tile[r][c4+1] = v.y; tile[r][c4+2] = v.z; tile[r][c4+3] = v.w;
        __syncthreads();
        short4 o;
        o.x = f2bf(tile[c4+0][r]); o.y = f2bf(tile[c4+1][r]);
        o.z = f2bf(tile[c4+2][r]); o.w = f2bf(tile[c4+3][r]);
        *(short4*)(dst + (size_t)(n_off + n0 + r) * Ksz + k0 + c4) = o;
    } else {
        int row = id - 2432;
        int t = threadIdx.x;
        const float* xr = x + (size_t)row * D_;
        float4 v = *(const float4*)(xr + t * 4);
        float s  = v.x + v.y + v.z + v.w;
        float s2 = v.x*v.x + v.y*v.y + v.z*v.z + v.w*v.w;
        #pragma unroll
        for (int m = 1; m < 64; m <<= 1) { s += __shfl_xor(s, m); s2 += __shfl_xor(s2, m); }
        __shared__ float ps[4], ps2[4];
        if ((t & 63) == 0) { ps[t >> 6] = s; ps2[t >> 6] = s2; }
        __syncthreads();
        s  = ps[0] + ps[1] + ps[2] + ps[3];
        s2 = ps2[0] + ps2[1] + ps2[2] + ps2[3];
        float mu  = s * (1.0f / D_);
        float var = s2 * (1.0f / D_) - mu * mu;
        float inv = rsqrtf(var + 1e-5f);
        float4 wv = *(const float4*)(lnw + t * 4);
        float4 bv = *(const float4*)(lnb + t * 4);
        short4 o;
        o.x = f2bf((v.x - mu) * inv * wv.x + bv.x);
        o.y = f2bf((v.y - mu) * inv * wv.y + bv.y);
        o.z = f2bf((v.z - mu) * inv * wv.z + bv.z);
        o.w = f2bf((v.w - mu) * inv * wv.w + bv.w);
        *(short4*)(xn + (size_t)row * D_ + t * 4) = o;
    }
}

// ---------------------------------------------------------------------------
// K3/K8: bf16 GEMM, A [M][K] row-major, BT [N][K] row-major (B transposed).
// 128x128 tile, BK=32, EIGHT waves (2x4), mfma 16x16x32, 64x32 per wave.
// THREE-DEEP rotating pipeline with ONE barrier per K-step:
//   iter kt: ds_read buf[kt%3]; lgkmcnt(0); STAGE(tile kt+2 -> buf[(kt+2)%3]);
//   MFMA; vmcnt(2) (tile kt+1 landed, kt+2 in flight); s_barrier.
// WAR safety: buf[(kt+2)%3] was last read in iter kt-1; every wave's reads
// there were fenced by its own lgkmcnt(0) before the end-of-iter barrier,
// and max wave skew is one inter-barrier region where read buf (cur) and
// staged buf ((cur+2)%3) are always distinct mod 3.
// LDS swizzle (conflict-free + coalesced, both-sides involution):
//   element (row fr, k-slice g) at byte fr*64 + 16*(g ^ ((fr>>1)&3));
//   staging lane l covers row l>>2, k-slice (l&3)^((l>>3)&3).
// 1D grid with bijective XCD swizzle (gridDim.x % 8 == 0).
// MODE 0: C bf16, bias split (2048|128|128). MODE 1: C f32, bias + residual.
// ---------------------------------------------------------------------------
template <int MODE>
__global__ __launch_bounds__(512) void gemm_bt(const short* __restrict__ A,
                                               const short* __restrict__ BT,
                                               void* __restrict__ Cout,
                                               int M, int N, int K,
                                               const float* __restrict__ bias0,
                                               const float* __restrict__ bias1,
                                               const float* __restrict__ bias2,
                                               const float* __restrict__ resid) {
    __shared__ short lA[3][128 * 32];
    __shared__ short lB[3][128 * 32];
    const int nwg = gridDim.x;
    const int cpx = nwg >> 3;
    const int orig = blockIdx.x;
    const int wg = (orig & 7) * cpx + (orig >> 3);
    const int ntn = N >> 7;
    const int m0 = (wg / ntn) * 128, n0 = (wg % ntn) * 128;
    const int t = threadIdx.x, w = t >> 6, l = t & 63;
    const int wm = w >> 2, wn = w & 3;          // 2 x 4 wave grid
    const int sr = l >> 2;
    const int sg = (l & 3) ^ ((l >> 3) & 3);
    const int fr = l & 15, fg = l >> 4;
    const int frag_off = fr * 32 + 8 * (fg ^ ((fr >> 1) & 3));

    f32x4 acc[4][2];
    #pragma unroll
    for (int mi = 0; mi < 4; ++mi)
        #pragma unroll
        for (int ni = 0; ni < 2; ++ni) acc[mi][ni] = (f32x4){0.f, 0.f, 0.f, 0.f};

    auto STAGE = [&](int bi, int k0) {
        int row = w * 16 + sr;                  // wave w stages block w
        gload_lds16(A  + (size_t)(m0 + row) * K + k0 + sg * 8, &lA[bi][w * 512]);
        gload_lds16(BT + (size_t)(n0 + row) * K + k0 + sg * 8, &lB[bi][w * 512]);
    };

    const int NT = K >> 5;
    STAGE(0, 0);
    if (NT > 1) STAGE(1, 32);
    asm volatile("s_waitcnt vmcnt(2)" ::: "memory");   // tile-0 landed
    __builtin_amdgcn_s_barrier();

    int cur = 0, stg = 2;
    for (int kt = 0; kt < NT; ++kt) {
        bf16x8 af[4], bfr[2];
        #pragma unroll
        for (int mi = 0; mi < 4; ++mi)
            af[mi] = *(const bf16x8*)(&lA[cur][(wm * 4 + mi) * 512] + frag_off);
        #pragma unroll
        for (int ni = 0; ni < 2; ++ni)
            bfr[ni] = *(const bf16x8*)(&lB[cur][(wn * 2 + ni) * 512] + frag_off);
        asm volatile("s_waitcnt lgkmcnt(0)" ::: "memory");
        __builtin_amdgcn_sched_barrier(0);
        if (kt + 2 < NT) STAGE(stg, (kt + 2) << 5);
        __builtin_amdgcn_s_setprio(1);
        #pragma unroll
        for (int mi = 0; mi < 4; ++mi)
            #pragma unroll
            for (int ni = 0; ni < 2; ++ni)
                acc[mi][ni] = __builtin_amdgcn_mfma_f32_16x16x32_bf16(af[mi], bfr[ni], acc[mi][ni], 0, 0, 0);
        __builtin_amdgcn_s_setprio(0);
        if (kt + 1 < NT) {
            if (kt + 2 < NT) asm volatile("s_waitcnt vmcnt(2)" ::: "memory");
            else             asm volatile("s_waitcnt vmcnt(0)" ::: "memory");
            __builtin_amdgcn_sched_barrier(0);
            __builtin_amdgcn_s_barrier();    // buf[(cur+1)%3] holds tile kt+1
        }
        cur = (cur == 2) ? 0 : cur + 1;
        stg = (stg == 2) ? 0 : stg + 1;
    }

    const int cr = (l >> 4) * 4, cc = l & 15;
    #pragma unroll
    for (int mi = 0; mi < 4; ++mi)
        #pragma unroll
        for (int ni = 0; ni < 2; ++ni) {
            int col = n0 + wn * 32 + ni * 16 + cc;
            float badd;
            if (MODE == 0)
                badd = (col < 2048) ? bias0[col] : (col < 2176 ? bias1[col - 2048] : bias2[col - 2176]);
            else
                badd = bias0[col];
            #pragma unroll
            for (int e = 0; e < 4; ++e) {
                int row = m0 + wm * 64 + mi * 16 + cr + e;
                float vout = acc[mi][ni][e] + badd;
                if (MODE == 0) {
                    ((short*)Cout)[(size_t)row * N + col] = f2bf(vout);
                } else {
                    vout += resid[(size_t)row * N + col];
                    ((float*)Cout)[(size_t)row * N + col] = vout;
                }
            }
        }
}

// ---------------------------------------------------------------------------
// K4: sinkpass1 — fused {Sinkhorn + pass1}. One block per (chain,chunk),
// 256 threads = 4 waves. Wave w runs 8 sequential linear-space sinkhorns
// for timesteps w*8..w*8+7, writing gamma*P (bf16) into the LDS chunk image
// AND global Ahat, plus u into LDS + global. Then wave 0 runs the pass1
// transfer-matrix MFMA chain from LDS -> Mc (bf16) + vc.
// ---------------------------------------------------------------------------
__global__ __launch_bounds__(256) void sinkpass1_kernel(const short* __restrict__ Cp,
                                                        short* __restrict__ Ahat,
                                                        float* __restrict__ u_g,
                                                        short* __restrict__ Mc,
                                                        float* __restrict__ vc) {
    __shared__ short lAh[CHUNK * 256];   // 16 KB: matrix tt at lAh + tt*256
    __shared__ float lu[CHUNK * 16];     // 2 KB
    const int unit = blockIdx.x;            // chain*NCHUNK + c
    const int chain = unit >> 5, c = unit & 31;
    const int b = chain >> 3, hh = chain & 7;
    const int tid = threadIdx.x, w = tid >> 6, l = tid & 63;
    const int a = l >> 3, bl = l & 7;       // sinkhorn 2x2-block lane coords
    const int a32 = ((l ^ 32) << 2);

    for (int k = 0; k < 8; ++k) {
        const int tt = w * 8 + k;
        const int tok = b * S_ + c * CHUNK + tt;
        const short* base = Cp + (size_t)tok * NPROJ + hh * 256;
        short2 q0 = *(const short2*)(base + (2 * a)     * 16 + 2 * bl);
        short2 q1 = *(const short2*)(base + (2 * a + 1) * 16 + 2 * bl);
        float p00 = __expf(bf2f(q0.x)), p01 = __expf(bf2f(q0.y));
        float p10 = __expf(bf2f(q1.x)), p11 = __expf(bf2f(q1.y));
        #pragma unroll
        for (int it = 0; it < 5; ++it) {
            float r0 = p00 + p01, r1 = p10 + p11;
            r0 += dppmov<DPP_QX1>(r0);  r1 += dppmov<DPP_QX1>(r1);   // xor 1
            r0 += dppmov<DPP_QX2>(r0);  r1 += dppmov<DPP_QX2>(r1);   // xor 2
            r0 += dppmov<DPP_HMIR>(r0); r1 += dppmov<DPP_HMIR>(r1);  // xor 4
            float i0 = __builtin_amdgcn_rcpf(r0), i1 = __builtin_amdgcn_rcpf(r1);
            p00 *= i0; p01 *= i0; p10 *= i1; p11 *= i1;
            float c0 = p00 + p10, c1 = p01 + p11;
            c0 += dppmov<DPP_ROR8>(c0); c1 += dppmov<DPP_ROR8>(c1);  // xor 8
            c0 += swzf<0x401F>(c0);     c1 += swzf<0x401F>(c1);      // xor 16
            c0 += bpermf(a32, c0);      c1 += bpermf(a32, c1);       // xor 32
            float j0 = __builtin_amdgcn_rcpf(c0), j1 = __builtin_amdgcn_rcpf(c1);
            p00 *= j0; p10 *= j0; p01 *= j1; p11 *= j1;
        }
        short2 gp = *(const short2*)(Cp + (size_t)tok * NPROJ + 2048 + hh * 16 + 2 * a);
        short2 bn = *(const short2*)(Cp + (size_t)tok * NPROJ + 2176 + hh * 16 + 2 * a);
        float g0 = 1.f / (1.f + __expf(-bf2f(gp.x)));
        float g1 = 1.f / (1.f + __expf(-bf2f(gp.y)));
        short2 o0, o1;
        o0.x = f2bf(g0 * p00); o0.y = f2bf(g0 * p01);
        o1.x = f2bf(g1 * p10); o1.y = f2bf(g1 * p11);
        short* Al = lAh + tt * 256;
        *(short2*)(Al + (2 * a)     * 16 + 2 * bl) = o0;
        *(short2*)(Al + (2 * a + 1) * 16 + 2 * bl) = o1;
        short* Ag = Ahat + ((size_t)tok * H_ + hh) * 256;
        *(short2*)(Ag + (2 * a)     * 16 + 2 * bl) = o0;
        *(short2*)(Ag + (2 * a + 1) * 16 + 2 * bl) = o1;
        if (bl == 0) {
            float2 uu;
            uu.x = (1.f - g0) * bf2f(bn.x);
            uu.y = (1.f - g1) * bf2f(bn.y);
            *(float2*)(&lu[tt * 16 + 2 * a]) = uu;
            *(float2*)(u_g + ((size_t)tok * H_ + hh) * 16 + 2 * a) = uu;
        }
    }
    __syncthreads();

    // ---- pass1 chain (wave 0 only), from LDS image
    if (w == 0) {
        const int j = l & 15, g = l >> 4;
        bf16x8 mb = {0,0,0,0,0,0,0,0};
        bf16x8 vb = {0,0,0,0,0,0,0,0};
        #pragma unroll
        for (int e = 0; e < 4; ++e) if (4 * g + e == j) mb[e] = (short)0x3F80;  // I
        const f32x4 zero = {0.f, 0.f, 0.f, 0.f};
        f32x4 d = zero, dv = zero;
        #pragma unroll 4
        for (int tt = 0; tt < CHUNK; ++tt) {
            short4 pa = *(const short4*)(&lAh[tt * 256 + j * 16 + g * 4]);
            bf16x8 af = {0,0,0,0,0,0,0,0};
            af[0] = pa.x; af[1] = pa.y; af[2] = pa.z; af[3] = pa.w;
            d  = __builtin_amdgcn_mfma_f32_16x16x32_bf16(af, mb, zero, 0, 0, 0);
            dv = __builtin_amdgcn_mfma_f32_16x16x32_bf16(af, vb, zero, 0, 0, 0);
            if (j == 0) {
                dv[0] += lu[tt * 16 + 4 * g + 0];
                dv[1] += lu[tt * 16 + 4 * g + 1];
                dv[2] += lu[tt * 16 + 4 * g + 2];
                dv[3] += lu[tt * 16 + 4 * g + 3];
            }
            mb[0] = f2bf(d[0]);  mb[1] = f2bf(d[1]);  mb[2] = f2bf(d[2]);  mb[3] = f2bf(d[3]);
            vb[0] = f2bf(dv[0]); vb[1] = f2bf(dv[1]); vb[2] = f2bf(dv[2]); vb[3] = f2bf(dv[3]);
        }
        short* Mo = Mc + (size_t)unit * 256;
        #pragma unroll
        for (int e = 0; e < 4; ++e) Mo[(4 * g + e) * 16 + j] = mb[e];   // bf16
        if (j == 0) {
            #pragma unroll
            for (int e = 0; e < 4; ++e) vc[(size_t)unit * 16 + 4 * g + e] = dv[e];
        }
    }
}

// ---------------------------------------------------------------------------
// K6: pass23 — merged pass2+pass3. Per (chain,c) block: stage Ahat chunk +
// u chunk + Mc[0..c) + vc[0..c) into LDS (one vmcnt(0)), recompute own
// prefix (c steps, redundant-but-parallel), then 32 chain steps -> hs.
// ---------------------------------------------------------------------------
__global__ __launch_bounds__(64) void pass23_kernel(const short* __restrict__ Ahat,
                                                    const float* __restrict__ u,
                                                    const short* __restrict__ Mc,
                                                    const float* __restrict__ vc,
                                                    short* __restrict__ hs) {
    __shared__ short mats[64 * 256];   // 32 KB
    __shared__ float vecs[64 * 16];    // 4 KB
    int unit = blockIdx.x;
    int chain = unit >> 5, c = unit & 31;
    int b = chain >> 3, hh = chain & 7;
    int l = threadIdx.x, i = l & 15, g = l >> 4;
    const size_t id0 = ((size_t)(b * S_ + c * CHUNK)) * H_ + hh;

    #pragma unroll
    for (int q = 0; q < 16; ++q) {
        int m = q * 2 + (l >> 5);
        gload_lds16(Ahat + (id0 + (size_t)m * H_) * 256 + (l & 31) * 8,
                    (char*)mats + q * 1024);
    }
    #pragma unroll
    for (int q = 0; q < 2; ++q) {
        int sl = q * 16 + (l >> 2);
        gload_lds16(u + (id0 + (size_t)sl * H_) * 16 + (l & 3) * 4,
                    (char*)vecs + q * 1024);
    }
    const short* McB = Mc + (size_t)chain * NCHUNK * 256;
    const int nmc = (c + 1) >> 1;
    for (int q = 0; q < nmc; ++q)
        gload_lds16(McB + q * 512 + l * 8, (char*)mats + 16384 + q * 1024);
    const float* vcB = vc + (size_t)chain * NCHUNK * 16;
    const int nvc = (c + 15) >> 4;
    for (int q = 0; q < nvc; ++q)
        gload_lds16(vcB + q * 256 + l * 4, (char*)vecs + 2048 + q * 1024);

    asm volatile("s_waitcnt vmcnt(0)" ::: "memory");

    float h_0 = 0.f, h_1 = 0.f, h_2 = 0.f, h_3 = 0.f;   // h[4g..4g+3]
    for (int cc = 0; cc < c; ++cc) {
        short4 pa = *(const short4*)(&mats[(32 + cc) * 256 + i * 16 + g * 4]);
        float part = bf2f(pa.x) * h_0 + bf2f(pa.y) * h_1 + bf2f(pa.z) * h_2 + bf2f(pa.w) * h_3;
        part += __shfl_xor(part, 16);
        part += __shfl_xor(part, 32);
        float hnew = part + vecs[(32 + cc) * 16 + i];
        h_0 = __shfl(hnew, 4 * g + 0);
        h_1 = __shfl(hnew, 4 * g + 1);
        h_2 = __shfl(hnew, 4 * g + 2);
        h_3 = __shfl(hnew, 4 * g + 3);
    }
    #pragma unroll 4
    for (int tt = 0; tt < CHUNK; ++tt) {
        size_t r = (size_t)b * S_ + c * CHUNK + tt;
        short4 pa = *(const short4*)(&mats[tt * 256 + i * 16 + g * 4]);
        float part = bf2f(pa.x) * h_0 + bf2f(pa.y) * h_1 + bf2f(pa.z) * h_2 + bf2f(pa.w) * h_3;
        part += __shfl_xor(part, 16);
        part += __shfl_xor(part, 32);
        float hnew = part + vecs[tt * 16 + i];
        if (g == 0) hs[r * 128 + hh * 16 + i] = f2bf(hnew);
        h_0 = __shfl(hnew, 4 * g + 0);
        h_1 = __shfl(hnew, 4 * g + 1);
        h_2 = __shfl(hnew, 4 * g + 2);
        h_3 = __shfl(hnew, 4 * g + 3);
    }
}

// ---------------------------------------------------------------------------
// launch
// ---------------------------------------------------------------------------
extern "C" void kernel_launch(void* const* d_in, const int* in_sizes, int n_in,
                              void* d_out, int out_size, void* d_ws, size_t ws_size,
                              hipStream_t stream) {
    const float* x    = (const float*)d_in[0];
    const float* ln_w = (const float*)d_in[1];
    const float* ln_b = (const float*)d_in[2];
    const float* Wp   = (const float*)d_in[3];
    const float* bp   = (const float*)d_in[4];
    const float* Wg   = (const float*)d_in[5];
    const float* bg   = (const float*)d_in[6];
    const float* Wi   = (const float*)d_in[7];
    const float* bi   = (const float*)d_in[8];
    const float* Wo   = (const float*)d_in[9];
    const float* bo   = (const float*)d_in[10];
    float* out = (float*)d_out;

    char* ws = (char*)d_ws;
    constexpr size_t OFF_WCATT = 0;
    constexpr size_t OFF_WOT   = OFF_WCATT + (size_t)NPROJ * D_ * 2;
    constexpr size_t OFF_XN    = OFF_WOT   + (size_t)D_ * 128 * 2;
    constexpr size_t OFF_CP    = OFF_XN    + (size_t)TOK * D_ * 2;
    constexpr size_t OFF_AHAT  = OFF_CP    + (size_t)TOK * NPROJ * 2;      // Cp bf16
    constexpr size_t OFF_U     = OFF_AHAT  + (size_t)TOK * H_ * 256 * 2;
    constexpr size_t OFF_MC    = OFF_U     + (size_t)TOK * H_ * 16 * 4;
    constexpr size_t OFF_VC    = OFF_MC    + (size_t)NCHAIN * NCHUNK * 256 * 2;  // Mc bf16
    constexpr size_t OFF_HS    = OFF_VC    + (size_t)NCHAIN * NCHUNK * 16 * 4;

    short* WcatT = (short*)(ws + OFF_WCATT);
    short* WoT   = (short*)(ws + OFF_WOT);
    short* xn    = (short*)(ws + OFF_XN);
    short* Cp    = (short*)(ws + OFF_CP);
    short* Ahat  = (short*)(ws + OFF_AHAT);
    float* u     = (float*)(ws + OFF_U);
    short* Mc    = (short*)(ws + OFF_MC);
    float* vc    = (float*)(ws + OFF_VC);
    short* hs    = (short*)(ws + OFF_HS);

    // K1: merged weight transpose-casts + LayerNorm
    prep_kernel<<<2432 + TOK, 256, 0, stream>>>(Wp, Wg, Wi, Wo, WcatT, WoT,
                                                x, ln_w, ln_b, xn);
    // K3: fused projection GEMM [4096,1024]x[1024,2304] + bias -> bf16 Cp
    gemm_bt<0><<<(NPROJ / 128) * (TOK / 128), 512, 0, stream>>>(
        xn, WcatT, (void*)Cp, TOK, NPROJ, 1024, bp, bg, bi, nullptr);
    // K4: fused Sinkhorn + pass1 -> Ahat, u, Mc (bf16), vc
    sinkpass1_kernel<<<NCHAIN * NCHUNK, 256, 0, stream>>>(Cp, Ahat, u, Mc, vc);
    // K6: merged prefix-recompute + within-chunk recurrence -> hs (bf16)
    pass23_kernel<<<NCHAIN * NCHUNK, 64, 0, stream>>>(Ahat, u, Mc, vc, hs);
    // K8: output GEMM [4096,128]x[128,1024] + bo + residual -> f32 out
    gemm_bt<1><<<(D_ / 128) * (TOK / 128), 512, 0, stream>>>(
        hs, WoT, (void*)out, TOK, D_, 128, bo, nullptr, nullptr, x);
}

// Round 19
// 86.242 us; speedup vs baseline: 1.0285x; 1.0285x over previous
//
#include <hip/hip_runtime.h>
#include <hip/hip_bf16.h>

// ---- problem constants ----
#define D_    1024
#define H_    8
#define N_    16
#define B_    4
#define S_    1024
#define TOK   (B_*S_)       // 4096 tokens
#define NPROJ 2304          // 2048 (perm) + 128 (gate) + 128 (input)
#define CHUNK 32
#define NCHUNK (S_/CHUNK)   // 32
#define NCHAIN (B_*H_)      // 32

typedef __attribute__((ext_vector_type(8))) short bf16x8;
typedef __attribute__((ext_vector_type(4))) float f32x4;

typedef __attribute__((address_space(3))) void       as3_void;
typedef const __attribute__((address_space(1))) void as1_void;

__device__ __forceinline__ void gload_lds16(const void* g, void* l) {
    __builtin_amdgcn_global_load_lds((as1_void*)g, (as3_void*)l, 16, 0, 0);
}

__device__ __forceinline__ short f2bf(float f) {
    unsigned u = __builtin_bit_cast(unsigned, f);
    unsigned r = 0x7FFFu + ((u >> 16) & 1u);
    return (short)((u + r) >> 16);
}
__device__ __forceinline__ float bf2f(short s) {
    unsigned u = ((unsigned)(unsigned short)s) << 16;
    return __builtin_bit_cast(float, u);
}

// single-instruction lane swizzle (xor patterns within 32-lane halves)
template <int IMM>
__device__ __forceinline__ float swzf(float x) {
    return __builtin_bit_cast(float,
        __builtin_amdgcn_ds_swizzle(__builtin_bit_cast(int, x), IMM));
}
// cross-32-lane pull with precomputed byte address
__device__ __forceinline__ float bpermf(int addr, float x) {
    return __builtin_bit_cast(float,
        __builtin_amdgcn_ds_bpermute(addr, __builtin_bit_cast(int, x)));
}
// DPP lane move (VALU pipe, no LDS): CTRL = quad_perm/row op encoding
template <int CTRL>
__device__ __forceinline__ float dppmov(float x) {
    return __builtin_bit_cast(float,
        __builtin_amdgcn_update_dpp(0, __builtin_bit_cast(int, x),
                                    CTRL, 0xF, 0xF, true));
}
#define DPP_QX1  0xB1   // quad_perm [1,0,3,2]  : xor 1
#define DPP_QX2  0x4E   // quad_perm [2,3,0,1]  : xor 2
#define DPP_HMIR 0x141  // row_half_mirror      : completes 8-lane reduce
#define DPP_ROR8 0x128  // row_ror:8            : xor 8 within 16-lane row

// ---------------------------------------------------------------------------
// K1: merged {weight transpose-casts + LayerNorm}, range-decoded 1D grid:
//   [0,2048) Wp | [2048,2176) Wg | [2176,2304) Wi | [2304,2432) Wo
//   [2432,6528) LayerNorm row (id-2432) -> xn
// ---------------------------------------------------------------------------
__global__ __launch_bounds__(256) void prep_kernel(const float* __restrict__ Wp,
                                                   const float* __restrict__ Wg,
                                                   const float* __restrict__ Wi,
                                                   const float* __restrict__ Wo,
                                                   short* __restrict__ WcatT,
                                                   short* __restrict__ WoT,
                                                   const float* __restrict__ x,
                                                   const float* __restrict__ lnw,
                                                   const float* __restrict__ lnb,
                                                   short* __restrict__ xn) {
    int id = blockIdx.x;
    if (id < 2432) {
        const float* src; short* dst; int srcW, Ksz, n_off, bx, by;
        if (id < 2048)      { src = Wp; dst = WcatT; srcW = 2048; Ksz = 1024; n_off = 0;
                              bx = id & 63;  by = id >> 6; }
        else if (id < 2176) { int q = id - 2048; src = Wg; dst = WcatT; srcW = 128; Ksz = 1024;
                              n_off = 2048; bx = q & 3; by = q >> 2; }
        else if (id < 2304) { int q = id - 2176; src = Wi; dst = WcatT; srcW = 128; Ksz = 1024;
                              n_off = 2176; bx = q & 3; by = q >> 2; }
        else                { int q = id - 2304; src = Wo; dst = WoT; srcW = 1024; Ksz = 128;
                              n_off = 0; bx = q & 31; by = q >> 5; }
        __shared__ float tile[32][33];
        int n0 = bx * 32, k0 = by * 32;
        int r  = threadIdx.x >> 3;
        int c4 = (threadIdx.x & 7) * 4;
        float4 v = *(const float4*)(src + (size_t)(k0 + r) * srcW + n0 + c4);
        tile[r][c4+0] = v.x; tile[r][c4+1] = v.y; tile[r][c4+2] = v.z; tile[r][c4+3] = v.w;
        __syncthreads();
        short4 o;
        o.x = f2bf(tile[c4+0][r]); o.y = f2bf(tile[c4+1][r]);
        o.z = f2bf(tile[c4+2][r]); o.w = f2bf(tile[c4+3][r]);
        *(short4*)(dst + (size_t)(n_off + n0 + r) * Ksz + k0 + c4) = o;
    } else {
        int row = id - 2432;
        int t = threadIdx.x;
        const float* xr = x + (size_t)row * D_;
        float4 v = *(const float4*)(xr + t * 4);
        float s  = v.x + v.y + v.z + v.w;
        float s2 = v.x*v.x + v.y*v.y + v.z*v.z + v.w*v.w;
        #pragma unroll
        for (int m = 1; m < 64; m <<= 1) { s += __shfl_xor(s, m); s2 += __shfl_xor(s2, m); }
        __shared__ float ps[4], ps2[4];
        if ((t & 63) == 0) { ps[t >> 6] = s; ps2[t >> 6] = s2; }
        __syncthreads();
        s  = ps[0] + ps[1] + ps[2] + ps[3];
        s2 = ps2[0] + ps2[1] + ps2[2] + ps2[3];
        float mu  = s * (1.0f / D_);
        float var = s2 * (1.0f / D_) - mu * mu;
        float inv = rsqrtf(var + 1e-5f);
        float4 wv = *(const float4*)(lnw + t * 4);
        float4 bv = *(const float4*)(lnb + t * 4);
        short4 o;
        o.x = f2bf((v.x - mu) * inv * wv.x + bv.x);
        o.y = f2bf((v.y - mu) * inv * wv.y + bv.y);
        o.z = f2bf((v.z - mu) * inv * wv.z + bv.z);
        o.w = f2bf((v.w - mu) * inv * wv.w + bv.w);
        *(short4*)(xn + (size_t)row * D_ + t * 4) = o;
    }
}

// ---------------------------------------------------------------------------
// K3/K8: bf16 GEMM, A [M][K] row-major, BT [N][K] row-major (B transposed).
// 128x128 tile, BK=32, EIGHT waves (2x4), mfma 16x16x32, 64x32 per wave.
// THREE-DEEP rotating pipeline with ONE barrier per K-step:
//   iter kt: ds_read buf[kt%3]; lgkmcnt(0); STAGE(tile kt+2 -> buf[(kt+2)%3]);
//   MFMA; vmcnt(2) (tile kt+1 landed, kt+2 in flight); s_barrier.
// WAR safety: buf[(kt+2)%3] was last read in iter kt-1; every wave's reads
// there were fenced by its own lgkmcnt(0) before the end-of-iter barrier,
// and max wave skew is one inter-barrier region where read buf (cur) and
// staged buf ((cur+2)%3) are always distinct mod 3.
// LDS swizzle (conflict-free + coalesced, both-sides involution):
//   element (row fr, k-slice g) at byte fr*64 + 16*(g ^ ((fr>>1)&3));
//   staging lane l covers row l>>2, k-slice (l&3)^((l>>3)&3).
// 1D grid with bijective XCD swizzle (gridDim.x % 8 == 0).
// MODE 0: C bf16, bias split (2048|128|128). MODE 1: C f32, bias + residual.
// ---------------------------------------------------------------------------
template <int MODE>
__global__ __launch_bounds__(512) void gemm_bt(const short* __restrict__ A,
                                               const short* __restrict__ BT,
                                               void* __restrict__ Cout,
                                               int M, int N, int K,
                                               const float* __restrict__ bias0,
                                               const float* __restrict__ bias1,
                                               const float* __restrict__ bias2,
                                               const float* __restrict__ resid) {
    __shared__ short lA[3][128 * 32];
    __shared__ short lB[3][128 * 32];
    const int nwg = gridDim.x;
    const int cpx = nwg >> 3;
    const int orig = blockIdx.x;
    const int wg = (orig & 7) * cpx + (orig >> 3);
    const int ntn = N >> 7;
    const int m0 = (wg / ntn) * 128, n0 = (wg % ntn) * 128;
    const int t = threadIdx.x, w = t >> 6, l = t & 63;
    const int wm = w >> 2, wn = w & 3;          // 2 x 4 wave grid
    const int sr = l >> 2;
    const int sg = (l & 3) ^ ((l >> 3) & 3);
    const int fr = l & 15, fg = l >> 4;
    const int frag_off = fr * 32 + 8 * (fg ^ ((fr >> 1) & 3));

    f32x4 acc[4][2];
    #pragma unroll
    for (int mi = 0; mi < 4; ++mi)
        #pragma unroll
        for (int ni = 0; ni < 2; ++ni) acc[mi][ni] = (f32x4){0.f, 0.f, 0.f, 0.f};

    auto STAGE = [&](int bi, int k0) {
        int row = w * 16 + sr;                  // wave w stages block w
        gload_lds16(A  + (size_t)(m0 + row) * K + k0 + sg * 8, &lA[bi][w * 512]);
        gload_lds16(BT + (size_t)(n0 + row) * K + k0 + sg * 8, &lB[bi][w * 512]);
    };

    const int NT = K >> 5;
    STAGE(0, 0);
    if (NT > 1) STAGE(1, 32);
    asm volatile("s_waitcnt vmcnt(2)" ::: "memory");   // tile-0 landed
    __builtin_amdgcn_s_barrier();

    int cur = 0, stg = 2;
    for (int kt = 0; kt < NT; ++kt) {
        bf16x8 af[4], bfr[2];
        #pragma unroll
        for (int mi = 0; mi < 4; ++mi)
            af[mi] = *(const bf16x8*)(&lA[cur][(wm * 4 + mi) * 512] + frag_off);
        #pragma unroll
        for (int ni = 0; ni < 2; ++ni)
            bfr[ni] = *(const bf16x8*)(&lB[cur][(wn * 2 + ni) * 512] + frag_off);
        asm volatile("s_waitcnt lgkmcnt(0)" ::: "memory");
        __builtin_amdgcn_sched_barrier(0);
        if (kt + 2 < NT) STAGE(stg, (kt + 2) << 5);
        __builtin_amdgcn_s_setprio(1);
        #pragma unroll
        for (int mi = 0; mi < 4; ++mi)
            #pragma unroll
            for (int ni = 0; ni < 2; ++ni)
                acc[mi][ni] = __builtin_amdgcn_mfma_f32_16x16x32_bf16(af[mi], bfr[ni], acc[mi][ni], 0, 0, 0);
        __builtin_amdgcn_s_setprio(0);
        if (kt + 1 < NT) {
            if (kt + 2 < NT) asm volatile("s_waitcnt vmcnt(2)" ::: "memory");
            else             asm volatile("s_waitcnt vmcnt(0)" ::: "memory");
            __builtin_amdgcn_sched_barrier(0);
            __builtin_amdgcn_s_barrier();    // buf[(cur+1)%3] holds tile kt+1
        }
        cur = (cur == 2) ? 0 : cur + 1;
        stg = (stg == 2) ? 0 : stg + 1;
    }

    const int cr = (l >> 4) * 4, cc = l & 15;
    #pragma unroll
    for (int mi = 0; mi < 4; ++mi)
        #pragma unroll
        for (int ni = 0; ni < 2; ++ni) {
            int col = n0 + wn * 32 + ni * 16 + cc;
            float badd;
            if (MODE == 0)
                badd = (col < 2048) ? bias0[col] : (col < 2176 ? bias1[col - 2048] : bias2[col - 2176]);
            else
                badd = bias0[col];
            #pragma unroll
            for (int e = 0; e < 4; ++e) {
                int row = m0 + wm * 64 + mi * 16 + cr + e;
                float vout = acc[mi][ni][e] + badd;
                if (MODE == 0) {
                    ((short*)Cout)[(size_t)row * N + col] = f2bf(vout);
                } else {
                    vout += resid[(size_t)row * N + col];
                    ((float*)Cout)[(size_t)row * N + col] = vout;
                }
            }
        }
}

// ---------------------------------------------------------------------------
// K4: sinkpass1 — fused {Sinkhorn + pass1}. One block per (chain,chunk),
// 512 threads = EIGHT waves. Wave w runs FOUR sequential linear-space
// sinkhorns for timesteps w*4..w*4+3 (restores VALU-latency hiding: 32
// waves/CU = 8/SIMD, vs 4/SIMD at 4-wave blocks), writing gamma*P (bf16)
// into the LDS chunk image AND global Ahat, plus u into LDS + global.
// Then wave 0 runs the pass1 transfer-matrix MFMA chain -> Mc (bf16) + vc.
// ---------------------------------------------------------------------------
__global__ __launch_bounds__(512) void sinkpass1_kernel(const short* __restrict__ Cp,
                                                        short* __restrict__ Ahat,
                                                        float* __restrict__ u_g,
                                                        short* __restrict__ Mc,
                                                        float* __restrict__ vc) {
    __shared__ short lAh[CHUNK * 256];   // 16 KB: matrix tt at lAh + tt*256
    __shared__ float lu[CHUNK * 16];     // 2 KB
    const int unit = blockIdx.x;            // chain*NCHUNK + c
    const int chain = unit >> 5, c = unit & 31;
    const int b = chain >> 3, hh = chain & 7;
    const int tid = threadIdx.x, w = tid >> 6, l = tid & 63;
    const int a = l >> 3, bl = l & 7;       // sinkhorn 2x2-block lane coords
    const int a32 = ((l ^ 32) << 2);

    for (int k = 0; k < 4; ++k) {
        const int tt = w * 4 + k;
        const int tok = b * S_ + c * CHUNK + tt;
        const short* base = Cp + (size_t)tok * NPROJ + hh * 256;
        short2 q0 = *(const short2*)(base + (2 * a)     * 16 + 2 * bl);
        short2 q1 = *(const short2*)(base + (2 * a + 1) * 16 + 2 * bl);
        float p00 = __expf(bf2f(q0.x)), p01 = __expf(bf2f(q0.y));
        float p10 = __expf(bf2f(q1.x)), p11 = __expf(bf2f(q1.y));
        #pragma unroll
        for (int it = 0; it < 5; ++it) {
            float r0 = p00 + p01, r1 = p10 + p11;
            r0 += dppmov<DPP_QX1>(r0);  r1 += dppmov<DPP_QX1>(r1);   // xor 1
            r0 += dppmov<DPP_QX2>(r0);  r1 += dppmov<DPP_QX2>(r1);   // xor 2
            r0 += dppmov<DPP_HMIR>(r0); r1 += dppmov<DPP_HMIR>(r1);  // xor 4
            float i0 = __builtin_amdgcn_rcpf(r0), i1 = __builtin_amdgcn_rcpf(r1);
            p00 *= i0; p01 *= i0; p10 *= i1; p11 *= i1;
            float c0 = p00 + p10, c1 = p01 + p11;
            c0 += dppmov<DPP_ROR8>(c0); c1 += dppmov<DPP_ROR8>(c1);  // xor 8
            c0 += swzf<0x401F>(c0);     c1 += swzf<0x401F>(c1);      // xor 16
            c0 += bpermf(a32, c0);      c1 += bpermf(a32, c1);       // xor 32
            float j0 = __builtin_amdgcn_rcpf(c0), j1 = __builtin_amdgcn_rcpf(c1);
            p00 *= j0; p10 *= j0; p01 *= j1; p11 *= j1;
        }
        short2 gp = *(const short2*)(Cp + (size_t)tok * NPROJ + 2048 + hh * 16 + 2 * a);
        short2 bn = *(const short2*)(Cp + (size_t)tok * NPROJ + 2176 + hh * 16 + 2 * a);
        float g0 = 1.f / (1.f + __expf(-bf2f(gp.x)));
        float g1 = 1.f / (1.f + __expf(-bf2f(gp.y)));
        short2 o0, o1;
        o0.x = f2bf(g0 * p00); o0.y = f2bf(g0 * p01);
        o1.x = f2bf(g1 * p10); o1.y = f2bf(g1 * p11);
        short* Al = lAh + tt * 256;
        *(short2*)(Al + (2 * a)     * 16 + 2 * bl) = o0;
        *(short2*)(Al + (2 * a + 1) * 16 + 2 * bl) = o1;
        short* Ag = Ahat + ((size_t)tok * H_ + hh) * 256;
        *(short2*)(Ag + (2 * a)     * 16 + 2 * bl) = o0;
        *(short2*)(Ag + (2 * a + 1) * 16 + 2 * bl) = o1;
        if (bl == 0) {
            float2 uu;
            uu.x = (1.f - g0) * bf2f(bn.x);
            uu.y = (1.f - g1) * bf2f(bn.y);
            *(float2*)(&lu[tt * 16 + 2 * a]) = uu;
            *(float2*)(u_g + ((size_t)tok * H_ + hh) * 16 + 2 * a) = uu;
        }
    }
    __syncthreads();

    // ---- pass1 chain (wave 0 only), from LDS image
    if (w == 0) {
        const int j = l & 15, g = l >> 4;
        bf16x8 mb = {0,0,0,0,0,0,0,0};
        bf16x8 vb = {0,0,0,0,0,0,0,0};
        #pragma unroll
        for (int e = 0; e < 4; ++e) if (4 * g + e == j) mb[e] = (short)0x3F80;  // I
        const f32x4 zero = {0.f, 0.f, 0.f, 0.f};
        f32x4 d = zero, dv = zero;
        #pragma unroll 4
        for (int tt = 0; tt < CHUNK; ++tt) {
            short4 pa = *(const short4*)(&lAh[tt * 256 + j * 16 + g * 4]);
            bf16x8 af = {0,0,0,0,0,0,0,0};
            af[0] = pa.x; af[1] = pa.y; af[2] = pa.z; af[3] = pa.w;
            d  = __builtin_amdgcn_mfma_f32_16x16x32_bf16(af, mb, zero, 0, 0, 0);
            dv = __builtin_amdgcn_mfma_f32_16x16x32_bf16(af, vb, zero, 0, 0, 0);
            if (j == 0) {
                dv[0] += lu[tt * 16 + 4 * g + 0];
                dv[1] += lu[tt * 16 + 4 * g + 1];
                dv[2] += lu[tt * 16 + 4 * g + 2];
                dv[3] += lu[tt * 16 + 4 * g + 3];
            }
            mb[0] = f2bf(d[0]);  mb[1] = f2bf(d[1]);  mb[2] = f2bf(d[2]);  mb[3] = f2bf(d[3]);
            vb[0] = f2bf(dv[0]); vb[1] = f2bf(dv[1]); vb[2] = f2bf(dv[2]); vb[3] = f2bf(dv[3]);
        }
        short* Mo = Mc + (size_t)unit * 256;
        #pragma unroll
        for (int e = 0; e < 4; ++e) Mo[(4 * g + e) * 16 + j] = mb[e];   // bf16
        if (j == 0) {
            #pragma unroll
            for (int e = 0; e < 4; ++e) vc[(size_t)unit * 16 + 4 * g + e] = dv[e];
        }
    }
}

// ---------------------------------------------------------------------------
// K6: pass23 — merged pass2+pass3. Per (chain,c) block: stage Ahat chunk +
// u chunk + Mc[0..c) + vc[0..c) into LDS (one vmcnt(0)), recompute own
// prefix (c steps, redundant-but-parallel), then 32 chain steps -> hs.
// ---------------------------------------------------------------------------
__global__ __launch_bounds__(64) void pass23_kernel(const short* __restrict__ Ahat,
                                                    const float* __restrict__ u,
                                                    const short* __restrict__ Mc,
                                                    const float* __restrict__ vc,
                                                    short* __restrict__ hs) {
    __shared__ short mats[64 * 256];   // 32 KB
    __shared__ float vecs[64 * 16];    // 4 KB
    int unit = blockIdx.x;
    int chain = unit >> 5, c = unit & 31;
    int b = chain >> 3, hh = chain & 7;
    int l = threadIdx.x, i = l & 15, g = l >> 4;
    const size_t id0 = ((size_t)(b * S_ + c * CHUNK)) * H_ + hh;

    #pragma unroll
    for (int q = 0; q < 16; ++q) {
        int m = q * 2 + (l >> 5);
        gload_lds16(Ahat + (id0 + (size_t)m * H_) * 256 + (l & 31) * 8,
                    (char*)mats + q * 1024);
    }
    #pragma unroll
    for (int q = 0; q < 2; ++q) {
        int sl = q * 16 + (l >> 2);
        gload_lds16(u + (id0 + (size_t)sl * H_) * 16 + (l & 3) * 4,
                    (char*)vecs + q * 1024);
    }
    const short* McB = Mc + (size_t)chain * NCHUNK * 256;
    const int nmc = (c + 1) >> 1;
    for (int q = 0; q < nmc; ++q)
        gload_lds16(McB + q * 512 + l * 8, (char*)mats + 16384 + q * 1024);
    const float* vcB = vc + (size_t)chain * NCHUNK * 16;
    const int nvc = (c + 15) >> 4;
    for (int q = 0; q < nvc; ++q)
        gload_lds16(vcB + q * 256 + l * 4, (char*)vecs + 2048 + q * 1024);

    asm volatile("s_waitcnt vmcnt(0)" ::: "memory");

    float h_0 = 0.f, h_1 = 0.f, h_2 = 0.f, h_3 = 0.f;   // h[4g..4g+3]
    for (int cc = 0; cc < c; ++cc) {
        short4 pa = *(const short4*)(&mats[(32 + cc) * 256 + i * 16 + g * 4]);
        float part = bf2f(pa.x) * h_0 + bf2f(pa.y) * h_1 + bf2f(pa.z) * h_2 + bf2f(pa.w) * h_3;
        part += __shfl_xor(part, 16);
        part += __shfl_xor(part, 32);
        float hnew = part + vecs[(32 + cc) * 16 + i];
        h_0 = __shfl(hnew, 4 * g + 0);
        h_1 = __shfl(hnew, 4 * g + 1);
        h_2 = __shfl(hnew, 4 * g + 2);
        h_3 = __shfl(hnew, 4 * g + 3);
    }
    #pragma unroll 4
    for (int tt = 0; tt < CHUNK; ++tt) {
        size_t r = (size_t)b * S_ + c * CHUNK + tt;
        short4 pa = *(const short4*)(&mats[tt * 256 + i * 16 + g * 4]);
        float part = bf2f(pa.x) * h_0 + bf2f(pa.y) * h_1 + bf2f(pa.z) * h_2 + bf2f(pa.w) * h_3;
        part += __shfl_xor(part, 16);
        part += __shfl_xor(part, 32);
        float hnew = part + vecs[tt * 16 + i];
        if (g == 0) hs[r * 128 + hh * 16 + i] = f2bf(hnew);
        h_0 = __shfl(hnew, 4 * g + 0);
        h_1 = __shfl(hnew, 4 * g + 1);
        h_2 = __shfl(hnew, 4 * g + 2);
        h_3 = __shfl(hnew, 4 * g + 3);
    }
}

// ---------------------------------------------------------------------------
// launch
// ---------------------------------------------------------------------------
extern "C" void kernel_launch(void* const* d_in, const int* in_sizes, int n_in,
                              void* d_out, int out_size, void* d_ws, size_t ws_size,
                              hipStream_t stream) {
    const float* x    = (const float*)d_in[0];
    const float* ln_w = (const float*)d_in[1];
    const float* ln_b = (const float*)d_in[2];
    const float* Wp   = (const float*)d_in[3];
    const float* bp   = (const float*)d_in[4];
    const float* Wg   = (const float*)d_in[5];
    const float* bg   = (const float*)d_in[6];
    const float* Wi   = (const float*)d_in[7];
    const float* bi   = (const float*)d_in[8];
    const float* Wo   = (const float*)d_in[9];
    const float* bo   = (const float*)d_in[10];
    float* out = (float*)d_out;

    char* ws = (char*)d_ws;
    constexpr size_t OFF_WCATT = 0;
    constexpr size_t OFF_WOT   = OFF_WCATT + (size_t)NPROJ * D_ * 2;
    constexpr size_t OFF_XN    = OFF_WOT   + (size_t)D_ * 128 * 2;
    constexpr size_t OFF_CP    = OFF_XN    + (size_t)TOK * D_ * 2;
    constexpr size_t OFF_AHAT  = OFF_CP    + (size_t)TOK * NPROJ * 2;      // Cp bf16
    constexpr size_t OFF_U     = OFF_AHAT  + (size_t)TOK * H_ * 256 * 2;
    constexpr size_t OFF_MC    = OFF_U     + (size_t)TOK * H_ * 16 * 4;
    constexpr size_t OFF_VC    = OFF_MC    + (size_t)NCHAIN * NCHUNK * 256 * 2;  // Mc bf16
    constexpr size_t OFF_HS    = OFF_VC    + (size_t)NCHAIN * NCHUNK * 16 * 4;

    short* WcatT = (short*)(ws + OFF_WCATT);
    short* WoT   = (short*)(ws + OFF_WOT);
    short* xn    = (short*)(ws + OFF_XN);
    short* Cp    = (short*)(ws + OFF_CP);
    short* Ahat  = (short*)(ws + OFF_AHAT);
    float* u     = (float*)(ws + OFF_U);
    short* Mc    = (short*)(ws + OFF_MC);
    float* vc    = (float*)(ws + OFF_VC);
    short* hs    = (short*)(ws + OFF_HS);

    // K1: merged weight transpose-casts + LayerNorm
    prep_kernel<<<2432 + TOK, 256, 0, stream>>>(Wp, Wg, Wi, Wo, WcatT, WoT,
                                                x, ln_w, ln_b, xn);
    // K3: fused projection GEMM [4096,1024]x[1024,2304] + bias -> bf16 Cp
    gemm_bt<0><<<(NPROJ / 128) * (TOK / 128), 512, 0, stream>>>(
        xn, WcatT, (void*)Cp, TOK, NPROJ, 1024, bp, bg, bi, nullptr);
    // K4: fused Sinkhorn + pass1 (8 waves) -> Ahat, u, Mc (bf16), vc
    sinkpass1_kernel<<<NCHAIN * NCHUNK, 512, 0, stream>>>(Cp, Ahat, u, Mc, vc);
    // K6: merged prefix-recompute + within-chunk recurrence -> hs (bf16)
    pass23_kernel<<<NCHAIN * NCHUNK, 64, 0, stream>>>(Ahat, u, Mc, vc, hs);
    // K8: output GEMM [4096,128]x[128,1024] + bo + residual -> f32 out
    gemm_bt<1><<<(D_ / 128) * (TOK / 128), 512, 0, stream>>>(
        hs, WoT, (void*)out, TOK, D_, 128, bo, nullptr, nullptr, x);
}

// Round 20
// 85.904 us; speedup vs baseline: 1.0326x; 1.0039x over previous
//
#include <hip/hip_runtime.h>
#include <hip/hip_bf16.h>

// ---- problem constants ----
#define D_    1024
#define H_    8
#define N_    16
#define B_    4
#define S_    1024
#define TOK   (B_*S_)       // 4096 tokens
#define NPROJ 2304          // 2048 (perm) + 128 (gate) + 128 (input)
#define CHUNK 32
#define NCHUNK (S_/CHUNK)   // 32
#define NCHAIN (B_*H_)      // 32

typedef __attribute__((ext_vector_type(8))) short bf16x8;
typedef __attribute__((ext_vector_type(4))) float f32x4;

typedef __attribute__((address_space(3))) void       as3_void;
typedef const __attribute__((address_space(1))) void as1_void;

__device__ __forceinline__ void gload_lds16(const void* g, void* l) {
    __builtin_amdgcn_global_load_lds((as1_void*)g, (as3_void*)l, 16, 0, 0);
}

__device__ __forceinline__ short f2bf(float f) {
    unsigned u = __builtin_bit_cast(unsigned, f);
    unsigned r = 0x7FFFu + ((u >> 16) & 1u);
    return (short)((u + r) >> 16);
}
__device__ __forceinline__ float bf2f(short s) {
    unsigned u = ((unsigned)(unsigned short)s) << 16;
    return __builtin_bit_cast(float, u);
}

// single-instruction lane swizzle (xor patterns within 32-lane halves)
template <int IMM>
__device__ __forceinline__ float swzf(float x) {
    return __builtin_bit_cast(float,
        __builtin_amdgcn_ds_swizzle(__builtin_bit_cast(int, x), IMM));
}
// cross-32-lane pull with precomputed byte address
__device__ __forceinline__ float bpermf(int addr, float x) {
    return __builtin_bit_cast(float,
        __builtin_amdgcn_ds_bpermute(addr, __builtin_bit_cast(int, x)));
}
// DPP lane move (VALU pipe, no LDS): CTRL = quad_perm/row op encoding
template <int CTRL>
__device__ __forceinline__ float dppmov(float x) {
    return __builtin_bit_cast(float,
        __builtin_amdgcn_update_dpp(0, __builtin_bit_cast(int, x),
                                    CTRL, 0xF, 0xF, true));
}
#define DPP_QX1  0xB1   // quad_perm [1,0,3,2]  : xor 1
#define DPP_QX2  0x4E   // quad_perm [2,3,0,1]  : xor 2
#define DPP_HMIR 0x141  // row_half_mirror      : completes 8-lane reduce
#define DPP_ROR8 0x128  // row_ror:8            : xor 8 within 16-lane row

// ---------------------------------------------------------------------------
// K1: merged {weight transpose-casts + LayerNorm}, range-decoded 1D grid:
//   [0,2048) Wp | [2048,2176) Wg | [2176,2304) Wi | [2304,2432) Wo
//   [2432,6528) LayerNorm row (id-2432) -> xn
// ---------------------------------------------------------------------------
__global__ __launch_bounds__(256) void prep_kernel(const float* __restrict__ Wp,
                                                   const float* __restrict__ Wg,
                                                   const float* __restrict__ Wi,
                                                   const float* __restrict__ Wo,
                                                   short* __restrict__ WcatT,
                                                   short* __restrict__ WoT,
                                                   const float* __restrict__ x,
                                                   const float* __restrict__ lnw,
                                                   const float* __restrict__ lnb,
                                                   short* __restrict__ xn) {
    int id = blockIdx.x;
    if (id < 2432) {
        const float* src; short* dst; int srcW, Ksz, n_off, bx, by;
        if (id < 2048)      { src = Wp; dst = WcatT; srcW = 2048; Ksz = 1024; n_off = 0;
                              bx = id & 63;  by = id >> 6; }
        else if (id < 2176) { int q = id - 2048; src = Wg; dst = WcatT; srcW = 128; Ksz = 1024;
                              n_off = 2048; bx = q & 3; by = q >> 2; }
        else if (id < 2304) { int q = id - 2176; src = Wi; dst = WcatT; srcW = 128; Ksz = 1024;
                              n_off = 2176; bx = q & 3; by = q >> 2; }
        else                { int q = id - 2304; src = Wo; dst = WoT; srcW = 1024; Ksz = 128;
                              n_off = 0; bx = q & 31; by = q >> 5; }
        __shared__ float tile[32][33];
        int n0 = bx * 32, k0 = by * 32;
        int r  = threadIdx.x >> 3;
        int c4 = (threadIdx.x & 7) * 4;
        float4 v = *(const float4*)(src + (size_t)(k0 + r) * srcW + n0 + c4);
        tile[r][c4+0] = v.x; tile[r][c4+1] = v.y; tile[r][c4+2] = v.z; tile[r][c4+3] = v.w;
        __syncthreads();
        short4 o;
        o.x = f2bf(tile[c4+0][r]); o.y = f2bf(tile[c4+1][r]);
        o.z = f2bf(tile[c4+2][r]); o.w = f2bf(tile[c4+3][r]);
        *(short4*)(dst + (size_t)(n_off + n0 + r) * Ksz + k0 + c4) = o;
    } else {
        int row = id - 2432;
        int t = threadIdx.x;
        const float* xr = x + (size_t)row * D_;
        float4 v = *(const float4*)(xr + t * 4);
        float s  = v.x + v.y + v.z + v.w;
        float s2 = v.x*v.x + v.y*v.y + v.z*v.z + v.w*v.w;
        #pragma unroll
        for (int m = 1; m < 64; m <<= 1) { s += __shfl_xor(s, m); s2 += __shfl_xor(s2, m); }
        __shared__ float ps[4], ps2[4];
        if ((t & 63) == 0) { ps[t >> 6] = s; ps2[t >> 6] = s2; }
        __syncthreads();
        s  = ps[0] + ps[1] + ps[2] + ps[3];
        s2 = ps2[0] + ps2[1] + ps2[2] + ps2[3];
        float mu  = s * (1.0f / D_);
        float var = s2 * (1.0f / D_) - mu * mu;
        float inv = rsqrtf(var + 1e-5f);
        float4 wv = *(const float4*)(lnw + t * 4);
        float4 bv = *(const float4*)(lnb + t * 4);
        short4 o;
        o.x = f2bf((v.x - mu) * inv * wv.x + bv.x);
        o.y = f2bf((v.y - mu) * inv * wv.y + bv.y);
        o.z = f2bf((v.z - mu) * inv * wv.z + bv.z);
        o.w = f2bf((v.w - mu) * inv * wv.w + bv.w);
        *(short4*)(xn + (size_t)row * D_ + t * 4) = o;
    }
}

// ---------------------------------------------------------------------------
// K3/K8: bf16 GEMM, A [M][K] row-major, BT [N][K] row-major (B transposed).
// 128x128 tile, BK=32, EIGHT waves (2x4), mfma 16x16x32, 64x32 per wave.
// THREE-DEEP rotating pipeline, ONE barrier per K-step, STAGE AT TOP:
//   iter kt: STAGE(tile kt+2 -> buf[(kt+2)%3]); ds_read buf[kt%3];
//   lgkmcnt(0); MFMA; vmcnt(2) (tile kt+1 landed, kt+2 in flight); barrier.
// WAR: buf[(kt+2)%3] holds tile kt-1; all waves' reads of it were fenced by
// their own lgkmcnt(0) before the barrier ending iter kt-1. RAW: tile kt's
// loads issued at top of kt-2 and drained by end-of-kt-1's vmcnt(2)+barrier.
// LDS swizzle (conflict-free + coalesced, both-sides involution):
//   element (row fr, k-slice g) at byte fr*64 + 16*(g ^ ((fr>>1)&3));
//   staging lane l covers row l>>2, k-slice (l&3)^((l>>3)&3).
// 1D grid with bijective XCD swizzle (gridDim.x % 8 == 0).
// MODE 0: C bf16, bias split (2048|128|128). MODE 1: C f32, bias + residual.
// ---------------------------------------------------------------------------
template <int MODE>
__global__ __launch_bounds__(512) void gemm_bt(const short* __restrict__ A,
                                               const short* __restrict__ BT,
                                               void* __restrict__ Cout,
                                               int M, int N, int K,
                                               const float* __restrict__ bias0,
                                               const float* __restrict__ bias1,
                                               const float* __restrict__ bias2,
                                               const float* __restrict__ resid) {
    __shared__ short lA[3][128 * 32];
    __shared__ short lB[3][128 * 32];
    const int nwg = gridDim.x;
    const int cpx = nwg >> 3;
    const int orig = blockIdx.x;
    const int wg = (orig & 7) * cpx + (orig >> 3);
    const int ntn = N >> 7;
    const int m0 = (wg / ntn) * 128, n0 = (wg % ntn) * 128;
    const int t = threadIdx.x, w = t >> 6, l = t & 63;
    const int wm = w >> 2, wn = w & 3;          // 2 x 4 wave grid
    const int sr = l >> 2;
    const int sg = (l & 3) ^ ((l >> 3) & 3);
    const int fr = l & 15, fg = l >> 4;
    const int frag_off = fr * 32 + 8 * (fg ^ ((fr >> 1) & 3));

    f32x4 acc[4][2];
    #pragma unroll
    for (int mi = 0; mi < 4; ++mi)
        #pragma unroll
        for (int ni = 0; ni < 2; ++ni) acc[mi][ni] = (f32x4){0.f, 0.f, 0.f, 0.f};

    auto STAGE = [&](int bi, int k0) {
        int row = w * 16 + sr;                  // wave w stages block w
        gload_lds16(A  + (size_t)(m0 + row) * K + k0 + sg * 8, &lA[bi][w * 512]);
        gload_lds16(BT + (size_t)(n0 + row) * K + k0 + sg * 8, &lB[bi][w * 512]);
    };

    const int NT = K >> 5;
    STAGE(0, 0);
    if (NT > 1) STAGE(1, 32);
    asm volatile("s_waitcnt vmcnt(2)" ::: "memory");   // tile-0 landed
    __builtin_amdgcn_s_barrier();

    int cur = 0, stg = 2;
    for (int kt = 0; kt < NT; ++kt) {
        if (kt + 2 < NT) STAGE(stg, (kt + 2) << 5);   // issue-early (top)
        bf16x8 af[4], bfr[2];
        #pragma unroll
        for (int mi = 0; mi < 4; ++mi)
            af[mi] = *(const bf16x8*)(&lA[cur][(wm * 4 + mi) * 512] + frag_off);
        #pragma unroll
        for (int ni = 0; ni < 2; ++ni)
            bfr[ni] = *(const bf16x8*)(&lB[cur][(wn * 2 + ni) * 512] + frag_off);
        asm volatile("s_waitcnt lgkmcnt(0)" ::: "memory");
        __builtin_amdgcn_sched_barrier(0);
        __builtin_amdgcn_s_setprio(1);
        #pragma unroll
        for (int mi = 0; mi < 4; ++mi)
            #pragma unroll
            for (int ni = 0; ni < 2; ++ni)
                acc[mi][ni] = __builtin_amdgcn_mfma_f32_16x16x32_bf16(af[mi], bfr[ni], acc[mi][ni], 0, 0, 0);
        __builtin_amdgcn_s_setprio(0);
        if (kt + 1 < NT) {
            if (kt + 2 < NT) asm volatile("s_waitcnt vmcnt(2)" ::: "memory");
            else             asm volatile("s_waitcnt vmcnt(0)" ::: "memory");
            __builtin_amdgcn_sched_barrier(0);
            __builtin_amdgcn_s_barrier();    // buf[(cur+1)%3] holds tile kt+1
        }
        cur = (cur == 2) ? 0 : cur + 1;
        stg = (stg == 2) ? 0 : stg + 1;
    }

    const int cr = (l >> 4) * 4, cc = l & 15;
    #pragma unroll
    for (int mi = 0; mi < 4; ++mi)
        #pragma unroll
        for (int ni = 0; ni < 2; ++ni) {
            int col = n0 + wn * 32 + ni * 16 + cc;
            float badd;
            if (MODE == 0)
                badd = (col < 2048) ? bias0[col] : (col < 2176 ? bias1[col - 2048] : bias2[col - 2176]);
            else
                badd = bias0[col];
            #pragma unroll
            for (int e = 0; e < 4; ++e) {
                int row = m0 + wm * 64 + mi * 16 + cr + e;
                float vout = acc[mi][ni][e] + badd;
                if (MODE == 0) {
                    ((short*)Cout)[(size_t)row * N + col] = f2bf(vout);
                } else {
                    vout += resid[(size_t)row * N + col];
                    ((float*)Cout)[(size_t)row * N + col] = vout;
                }
            }
        }
}

// ---------------------------------------------------------------------------
// K4: sinkpass1 — fused {Sinkhorn + pass1}. One block per (chain,chunk),
// 512 threads = EIGHT waves. Wave w runs FOUR sequential linear-space
// sinkhorns for timesteps w*4..w*4+3 (8 waves/SIMD hides VALU latency),
// writing gamma*P (bf16) into the LDS chunk image AND global Ahat, plus u
// into LDS + global. Then the pass1 tail is SPLIT: wave 0 runs the
// M-transfer chain (d/mb) -> Mc, wave 1 runs the independent v-response
// chain (dv/vb) -> vc, halving the serial tail.
// ---------------------------------------------------------------------------
__global__ __launch_bounds__(512) void sinkpass1_kernel(const short* __restrict__ Cp,
                                                        short* __restrict__ Ahat,
                                                        float* __restrict__ u_g,
                                                        short* __restrict__ Mc,
                                                        float* __restrict__ vc) {
    __shared__ short lAh[CHUNK * 256];   // 16 KB: matrix tt at lAh + tt*256
    __shared__ float lu[CHUNK * 16];     // 2 KB
    const int unit = blockIdx.x;            // chain*NCHUNK + c
    const int chain = unit >> 5, c = unit & 31;
    const int b = chain >> 3, hh = chain & 7;
    const int tid = threadIdx.x, w = tid >> 6, l = tid & 63;
    const int a = l >> 3, bl = l & 7;       // sinkhorn 2x2-block lane coords
    const int a32 = ((l ^ 32) << 2);

    for (int k = 0; k < 4; ++k) {
        const int tt = w * 4 + k;
        const int tok = b * S_ + c * CHUNK + tt;
        const short* base = Cp + (size_t)tok * NPROJ + hh * 256;
        short2 q0 = *(const short2*)(base + (2 * a)     * 16 + 2 * bl);
        short2 q1 = *(const short2*)(base + (2 * a + 1) * 16 + 2 * bl);
        float p00 = __expf(bf2f(q0.x)), p01 = __expf(bf2f(q0.y));
        float p10 = __expf(bf2f(q1.x)), p11 = __expf(bf2f(q1.y));
        #pragma unroll
        for (int it = 0; it < 5; ++it) {
            float r0 = p00 + p01, r1 = p10 + p11;
            r0 += dppmov<DPP_QX1>(r0);  r1 += dppmov<DPP_QX1>(r1);   // xor 1
            r0 += dppmov<DPP_QX2>(r0);  r1 += dppmov<DPP_QX2>(r1);   // xor 2
            r0 += dppmov<DPP_HMIR>(r0); r1 += dppmov<DPP_HMIR>(r1);  // xor 4
            float i0 = __builtin_amdgcn_rcpf(r0), i1 = __builtin_amdgcn_rcpf(r1);
            p00 *= i0; p01 *= i0; p10 *= i1; p11 *= i1;
            float c0 = p00 + p10, c1 = p01 + p11;
            c0 += dppmov<DPP_ROR8>(c0); c1 += dppmov<DPP_ROR8>(c1);  // xor 8
            c0 += swzf<0x401F>(c0);     c1 += swzf<0x401F>(c1);      // xor 16
            c0 += bpermf(a32, c0);      c1 += bpermf(a32, c1);       // xor 32
            float j0 = __builtin_amdgcn_rcpf(c0), j1 = __builtin_amdgcn_rcpf(c1);
            p00 *= j0; p10 *= j0; p01 *= j1; p11 *= j1;
        }
        short2 gp = *(const short2*)(Cp + (size_t)tok * NPROJ + 2048 + hh * 16 + 2 * a);
        short2 bn = *(const short2*)(Cp + (size_t)tok * NPROJ + 2176 + hh * 16 + 2 * a);
        float g0 = 1.f / (1.f + __expf(-bf2f(gp.x)));
        float g1 = 1.f / (1.f + __expf(-bf2f(gp.y)));
        short2 o0, o1;
        o0.x = f2bf(g0 * p00); o0.y = f2bf(g0 * p01);
        o1.x = f2bf(g1 * p10); o1.y = f2bf(g1 * p11);
        short* Al = lAh + tt * 256;
        *(short2*)(Al + (2 * a)     * 16 + 2 * bl) = o0;
        *(short2*)(Al + (2 * a + 1) * 16 + 2 * bl) = o1;
        short* Ag = Ahat + ((size_t)tok * H_ + hh) * 256;
        *(short2*)(Ag + (2 * a)     * 16 + 2 * bl) = o0;
        *(short2*)(Ag + (2 * a + 1) * 16 + 2 * bl) = o1;
        if (bl == 0) {
            float2 uu;
            uu.x = (1.f - g0) * bf2f(bn.x);
            uu.y = (1.f - g1) * bf2f(bn.y);
            *(float2*)(&lu[tt * 16 + 2 * a]) = uu;
            *(float2*)(u_g + ((size_t)tok * H_ + hh) * 16 + 2 * a) = uu;
        }
    }
    __syncthreads();

    // ---- pass1 tail, split: wave 0 = M-chain, wave 1 = v-chain
    if (w == 0) {
        const int j = l & 15, g = l >> 4;
        bf16x8 mb = {0,0,0,0,0,0,0,0};
        #pragma unroll
        for (int e = 0; e < 4; ++e) if (4 * g + e == j) mb[e] = (short)0x3F80;  // I
        const f32x4 zero = {0.f, 0.f, 0.f, 0.f};
        f32x4 d = zero;
        #pragma unroll 4
        for (int tt = 0; tt < CHUNK; ++tt) {
            short4 pa = *(const short4*)(&lAh[tt * 256 + j * 16 + g * 4]);
            bf16x8 af = {0,0,0,0,0,0,0,0};
            af[0] = pa.x; af[1] = pa.y; af[2] = pa.z; af[3] = pa.w;
            d = __builtin_amdgcn_mfma_f32_16x16x32_bf16(af, mb, zero, 0, 0, 0);
            mb[0] = f2bf(d[0]); mb[1] = f2bf(d[1]); mb[2] = f2bf(d[2]); mb[3] = f2bf(d[3]);
        }
        short* Mo = Mc + (size_t)unit * 256;
        #pragma unroll
        for (int e = 0; e < 4; ++e) Mo[(4 * g + e) * 16 + j] = mb[e];   // bf16
    } else if (w == 1) {
        const int j = l & 15, g = l >> 4;
        bf16x8 vb = {0,0,0,0,0,0,0,0};
        const f32x4 zero = {0.f, 0.f, 0.f, 0.f};
        f32x4 dv = zero;
        #pragma unroll 4
        for (int tt = 0; tt < CHUNK; ++tt) {
            short4 pa = *(const short4*)(&lAh[tt * 256 + j * 16 + g * 4]);
            bf16x8 af = {0,0,0,0,0,0,0,0};
            af[0] = pa.x; af[1] = pa.y; af[2] = pa.z; af[3] = pa.w;
            dv = __builtin_amdgcn_mfma_f32_16x16x32_bf16(af, vb, zero, 0, 0, 0);
            if (j == 0) {
                dv[0] += lu[tt * 16 + 4 * g + 0];
                dv[1] += lu[tt * 16 + 4 * g + 1];
                dv[2] += lu[tt * 16 + 4 * g + 2];
                dv[3] += lu[tt * 16 + 4 * g + 3];
            }
            vb[0] = f2bf(dv[0]); vb[1] = f2bf(dv[1]); vb[2] = f2bf(dv[2]); vb[3] = f2bf(dv[3]);
        }
        if (j == 0) {
            #pragma unroll
            for (int e = 0; e < 4; ++e) vc[(size_t)unit * 16 + 4 * g + e] = dv[e];
        }
    }
}

// ---------------------------------------------------------------------------
// K6: pass23 — merged pass2+pass3. Per (chain,c) block: stage Ahat chunk +
// u chunk + Mc[0..c) + vc[0..c) into LDS (one vmcnt(0)), recompute own
// prefix (c steps, redundant-but-parallel), then 32 chain steps -> hs.
// ---------------------------------------------------------------------------
__global__ __launch_bounds__(64) void pass23_kernel(const short* __restrict__ Ahat,
                                                    const float* __restrict__ u,
                                                    const short* __restrict__ Mc,
                                                    const float* __restrict__ vc,
                                                    short* __restrict__ hs) {
    __shared__ short mats[64 * 256];   // 32 KB
    __shared__ float vecs[64 * 16];    // 4 KB
    int unit = blockIdx.x;
    int chain = unit >> 5, c = unit & 31;
    int b = chain >> 3, hh = chain & 7;
    int l = threadIdx.x, i = l & 15, g = l >> 4;
    const size_t id0 = ((size_t)(b * S_ + c * CHUNK)) * H_ + hh;

    #pragma unroll
    for (int q = 0; q < 16; ++q) {
        int m = q * 2 + (l >> 5);
        gload_lds16(Ahat + (id0 + (size_t)m * H_) * 256 + (l & 31) * 8,
                    (char*)mats + q * 1024);
    }
    #pragma unroll
    for (int q = 0; q < 2; ++q) {
        int sl = q * 16 + (l >> 2);
        gload_lds16(u + (id0 + (size_t)sl * H_) * 16 + (l & 3) * 4,
                    (char*)vecs + q * 1024);
    }
    const short* McB = Mc + (size_t)chain * NCHUNK * 256;
    const int nmc = (c + 1) >> 1;
    for (int q = 0; q < nmc; ++q)
        gload_lds16(McB + q * 512 + l * 8, (char*)mats + 16384 + q * 1024);
    const float* vcB = vc + (size_t)chain * NCHUNK * 16;
    const int nvc = (c + 15) >> 4;
    for (int q = 0; q < nvc; ++q)
        gload_lds16(vcB + q * 256 + l * 4, (char*)vecs + 2048 + q * 1024);

    asm volatile("s_waitcnt vmcnt(0)" ::: "memory");

    float h_0 = 0.f, h_1 = 0.f, h_2 = 0.f, h_3 = 0.f;   // h[4g..4g+3]
    for (int cc = 0; cc < c; ++cc) {
        short4 pa = *(const short4*)(&mats[(32 + cc) * 256 + i * 16 + g * 4]);
        float part = bf2f(pa.x) * h_0 + bf2f(pa.y) * h_1 + bf2f(pa.z) * h_2 + bf2f(pa.w) * h_3;
        part += __shfl_xor(part, 16);
        part += __shfl_xor(part, 32);
        float hnew = part + vecs[(32 + cc) * 16 + i];
        h_0 = __shfl(hnew, 4 * g + 0);
        h_1 = __shfl(hnew, 4 * g + 1);
        h_2 = __shfl(hnew, 4 * g + 2);
        h_3 = __shfl(hnew, 4 * g + 3);
    }
    #pragma unroll 4
    for (int tt = 0; tt < CHUNK; ++tt) {
        size_t r = (size_t)b * S_ + c * CHUNK + tt;
        short4 pa = *(const short4*)(&mats[tt * 256 + i * 16 + g * 4]);
        float part = bf2f(pa.x) * h_0 + bf2f(pa.y) * h_1 + bf2f(pa.z) * h_2 + bf2f(pa.w) * h_3;
        part += __shfl_xor(part, 16);
        part += __shfl_xor(part, 32);
        float hnew = part + vecs[tt * 16 + i];
        if (g == 0) hs[r * 128 + hh * 16 + i] = f2bf(hnew);
        h_0 = __shfl(hnew, 4 * g + 0);
        h_1 = __shfl(hnew, 4 * g + 1);
        h_2 = __shfl(hnew, 4 * g + 2);
        h_3 = __shfl(hnew, 4 * g + 3);
    }
}

// ---------------------------------------------------------------------------
// launch
// ---------------------------------------------------------------------------
extern "C" void kernel_launch(void* const* d_in, const int* in_sizes, int n_in,
                              void* d_out, int out_size, void* d_ws, size_t ws_size,
                              hipStream_t stream) {
    const float* x    = (const float*)d_in[0];
    const float* ln_w = (const float*)d_in[1];
    const float* ln_b = (const float*)d_in[2];
    const float* Wp   = (const float*)d_in[3];
    const float* bp   = (const float*)d_in[4];
    const float* Wg   = (const float*)d_in[5];
    const float* bg   = (const float*)d_in[6];
    const float* Wi   = (const float*)d_in[7];
    const float* bi   = (const float*)d_in[8];
    const float* Wo   = (const float*)d_in[9];
    const float* bo   = (const float*)d_in[10];
    float* out = (float*)d_out;

    char* ws = (char*)d_ws;
    constexpr size_t OFF_WCATT = 0;
    constexpr size_t OFF_WOT   = OFF_WCATT + (size_t)NPROJ * D_ * 2;
    constexpr size_t OFF_XN    = OFF_WOT   + (size_t)D_ * 128 * 2;
    constexpr size_t OFF_CP    = OFF_XN    + (size_t)TOK * D_ * 2;
    constexpr size_t OFF_AHAT  = OFF_CP    + (size_t)TOK * NPROJ * 2;      // Cp bf16
    constexpr size_t OFF_U     = OFF_AHAT  + (size_t)TOK * H_ * 256 * 2;
    constexpr size_t OFF_MC    = OFF_U     + (size_t)TOK * H_ * 16 * 4;
    constexpr size_t OFF_VC    = OFF_MC    + (size_t)NCHAIN * NCHUNK * 256 * 2;  // Mc bf16
    constexpr size_t OFF_HS    = OFF_VC    + (size_t)NCHAIN * NCHUNK * 16 * 4;

    short* WcatT = (short*)(ws + OFF_WCATT);
    short* WoT   = (short*)(ws + OFF_WOT);
    short* xn    = (short*)(ws + OFF_XN);
    short* Cp    = (short*)(ws + OFF_CP);
    short* Ahat  = (short*)(ws + OFF_AHAT);
    float* u     = (float*)(ws + OFF_U);
    short* Mc    = (short*)(ws + OFF_MC);
    float* vc    = (float*)(ws + OFF_VC);
    short* hs    = (short*)(ws + OFF_HS);

    // K1: merged weight transpose-casts + LayerNorm
    prep_kernel<<<2432 + TOK, 256, 0, stream>>>(Wp, Wg, Wi, Wo, WcatT, WoT,
                                                x, ln_w, ln_b, xn);
    // K3: fused projection GEMM [4096,1024]x[1024,2304] + bias -> bf16 Cp
    gemm_bt<0><<<(NPROJ / 128) * (TOK / 128), 512, 0, stream>>>(
        xn, WcatT, (void*)Cp, TOK, NPROJ, 1024, bp, bg, bi, nullptr);
    // K4: fused Sinkhorn + pass1 (8 waves, split tail) -> Ahat, u, Mc, vc
    sinkpass1_kernel<<<NCHAIN * NCHUNK, 512, 0, stream>>>(Cp, Ahat, u, Mc, vc);
    // K6: merged prefix-recompute + within-chunk recurrence -> hs (bf16)
    pass23_kernel<<<NCHAIN * NCHUNK, 64, 0, stream>>>(Ahat, u, Mc, vc, hs);
    // K8: output GEMM [4096,128]x[128,1024] + bo + residual -> f32 out
    gemm_bt<1><<<(D_ / 128) * (TOK / 128), 512, 0, stream>>>(
        hs, WoT, (void*)out, TOK, D_, 128, bo, nullptr, nullptr, x);
}